// Round 10
// baseline (61.290 us; speedup 1.0000x reference)
//
#include <hip/hip_runtime.h>

#define NT   256
#define IMG  512
#define BT   32     // block output tile: 32x32
#define HSU  28     // sH col stride in uints (112B -> 2-way banks, min for b128)
#define WS_PARTIAL_OFF 1024   // floats; band table occupies first 2KB of ws

typedef _Float16 f16x8 __attribute__((ext_vector_type(8)));
typedef float    f32x4 __attribute__((ext_vector_type(4)));

__device__ inline unsigned pk2(float a, float b) {
    auto r = __builtin_amdgcn_cvt_pkrtz(a, b);     // f32x2 -> f16x2 (RTZ)
    return __builtin_bit_cast(unsigned, r);
}

// ---------------------------------------------------------------------------
// One-time init: per-lane MFMA band fragments for both conv passes -> ws.
// tab[l*8+0..3] = B1 frag (h-conv B operand), tab[l*8+4..7] = A2 frag.
// ---------------------------------------------------------------------------
__global__ void ssim_init_kernel(const float* __restrict__ kern,
                                 unsigned* __restrict__ tab) {
    const int l  = threadIdx.x;        // 0..63
    const int lm = l & 15;
    const int lg = l >> 4;
    const float invg = 1.0f / sqrtf(kern[60]);
    unsigned bu[4], au[4];
    #pragma unroll
    for (int jp = 0; jp < 4; ++jp) {
        const int k0 = 8 * lg + 2 * jp;
        const int d  = k0 - lm - 3;        // B1 band: w[k-n-3]
        const int e  = k0 - lm;            // A2 band: w[k-r]
        float b0 = 0.f, b1 = 0.f, a0 = 0.f, a1 = 0.f;
        if ((unsigned)d       <= 10u) b0 = kern[55 + d] * invg;
        if ((unsigned)(d + 1) <= 10u) b1 = kern[56 + d] * invg;
        if ((unsigned)e       <= 10u) a0 = kern[55 + e] * invg;
        if ((unsigned)(e + 1) <= 10u) a1 = kern[56 + e] * invg;
        bu[jp] = pk2(b0, b1);
        au[jp] = pk2(a0, a1);
    }
    *(uint4*)&tab[l * 8]     = make_uint4(bu[0], bu[1], bu[2], bu[3]);
    *(uint4*)&tab[l * 8 + 4] = make_uint4(au[0], au[1], au[2], au[3]);
}

// ---------------------------------------------------------------------------
// Load one H-conv A-fragment (8 f16 = 8 consecutive px) straight from global.
// gx is a multiple of 8 (float4-aligned). inb = block-uniform "all in bounds".
// ---------------------------------------------------------------------------
__device__ inline f16x8 frag_from_global(const float* __restrict__ img,
                                         int gy, int gx, bool inb) {
    float4 a = make_float4(0.f, 0.f, 0.f, 0.f), b = a;
    if (inb) {
        const float* r = img + gy * IMG;
        a = *(const float4*)(r + gx);
        b = *(const float4*)(r + gx + 4);
    } else if ((unsigned)gy < IMG) {
        const float* r = img + gy * IMG;
        if ((unsigned)gx < IMG)       a = *(const float4*)(r + gx);
        if ((unsigned)(gx + 4) < IMG) b = *(const float4*)(r + gx + 4);
    }
    return __builtin_bit_cast(f16x8, make_uint4(pk2(a.x, a.y), pk2(a.z, a.w),
                                                pk2(b.x, b.y), pk2(b.z, b.w)));
}

// ---------------------------------------------------------------------------
// SSIM via MFMA, v5. Changes vs v4 (44.8 us):
//  - NO raw-pixel LDS staging: each lane loads its H-conv A-fragment's 8 px
//    directly from global (2x float4 per image) and packs in-register. This
//    deletes the staging loop, 4 LDS ops/thread, and TWO barriers (3 -> 1
//    compute barriers). Costs 1.33x halo re-read from L1/L2 (HBM at 13%, ok).
// Math identical to v2..v4 (absmax 0.0039):
//   H-conv:  H[m][16ct+n]   = sum_k raw[m][16ct+k] * B1[k][n],  B1[k][n]=w[k-n-3]
//   V-conv:  out[16rt+r][n] = sum_k A2[r][k] * H[16rt+k][n],    A2[r][k]=w[k-r]
//   PP/TT/PT A-frags derived in-register as products of P/T frags.
// Fragment maps (gfx950 16x16x32): A: lane&15=m, k=(lane>>4)*8+j | B: lane&15=n,
//   same k | C: col=lane&15, row=(lane>>4)*4+reg.
// launch_bounds(256,4): round 4 showed squeezing further spills to scratch.
// ---------------------------------------------------------------------------
__global__ __launch_bounds__(NT, 4) void ssim_mfma_kernel(
    const float* __restrict__ pred,
    const float* __restrict__ target,
    const unsigned* __restrict__ tab,
    float* __restrict__ partial)
{
    __shared__ __align__(16) unsigned sH[5][BT][HSU];   // h-filtered, col-major
    __shared__ float sRed[4];

    const int tid = threadIdx.x;

    // ---- bijective XCD swizzle (gridDim.x % 8 == 0): XCD -> 8 whole images ----
    const int bid   = blockIdx.x;
    const int chunk = (int)gridDim.x >> 3;
    const int swz   = (bid & 7) * chunk + (bid >> 3);
    const int img   = swz >> 8;               // 256 tiles per 512x512 image
    const int rem   = swz & 255;
    const int tx0   = (rem & 15) * BT;
    const int ty0   = (rem >> 4) * BT;

    const int lane = tid & 63;
    const int wv   = tid >> 6;
    const int lm   = lane & 15;     // m (A row) / n (B col) / C col
    const int lg   = lane >> 4;     // k-group; C row-group

    const float* pimg = pred   + (size_t)img * (IMG * IMG);
    const float* timg = target + (size_t)img * (IMG * IMG);
    const bool interior = (tx0 > 0) && (tx0 < 480) && (ty0 > 0) && (ty0 < 480);

    // ---- H-conv A-fragments straight from global ----
    // job0 = wv (ct=wv&1, mt=wv>>1); job1 = wv+4 for wv<2 (ct=wv, mt=2)
    const int ct0 = wv & 1, mt0 = wv >> 1;
    const int gy0 = ty0 - 5 + mt0 * 16 + lm;
    const int gx0 = tx0 - 8 + 16 * ct0 + 8 * lg;
    const f16x8 aP0 = frag_from_global(pimg, gy0, gx0, interior);
    const f16x8 aT0 = frag_from_global(timg, gy0, gx0, interior);
    f16x8 aP1, aT1;
    if (wv < 2) {
        const int gy1 = ty0 + 27 + lm;              // mt=2
        const int gx1 = tx0 - 8 + 16 * wv + 8 * lg; // ct=wv
        aP1 = frag_from_global(pimg, gy1, gx1, interior);
        aT1 = frag_from_global(timg, gy1, gx1, interior);
    }

    // ---- band fragments: two L2-hit vector loads ----
    const f16x8 bfrag  = __builtin_bit_cast(f16x8, *(const uint4*)&tab[lane * 8]);
    const f16x8 a2frag = __builtin_bit_cast(f16x8, *(const uint4*)&tab[lane * 8 + 4]);
    const f32x4 zero4  = {0.f, 0.f, 0.f, 0.f};

    // ---- H-conv: mfma per channel, write h-filtered (f16) column-major ----
    {
        f16x8 af[5];
        af[0] = aP0; af[1] = aT0;
        af[2] = aP0 * aP0;                 // 4x v_pk_mul_f16 each
        af[3] = aT0 * aT0;
        af[4] = aP0 * aT0;
        #pragma unroll
        for (int ch = 0; ch < 5; ++ch) {
            const f32x4 h = __builtin_amdgcn_mfma_f32_16x16x32_f16(af[ch], bfrag, zero4, 0, 0, 0);
            *(uint2*)&sH[ch][16 * ct0 + lm][mt0 * 8 + 2 * lg] =
                make_uint2(pk2(h[0], h[1]), pk2(h[2], h[3]));
        }
    }
    if (wv < 2) {
        f16x8 af[5];
        af[0] = aP1; af[1] = aT1;
        af[2] = aP1 * aP1;
        af[3] = aT1 * aT1;
        af[4] = aP1 * aT1;
        #pragma unroll
        for (int ch = 0; ch < 5; ++ch) {
            const f32x4 h = __builtin_amdgcn_mfma_f32_16x16x32_f16(af[ch], bfrag, zero4, 0, 0, 0);
            *(uint2*)&sH[ch][16 * wv + lm][2 * 8 + 2 * lg] =
                make_uint2(pk2(h[0], h[1]), pk2(h[2], h[3]));
        }
    }
    __syncthreads();

    // ---- V-conv: each wave one 16x16 output quadrant, 5 channels ----
    const int rt  = wv >> 1;
    const int ct2 = wv & 1;
    f32x4 M[5];
    #pragma unroll
    for (int ch = 0; ch < 5; ++ch) {
        const f16x8 b2 = __builtin_bit_cast(f16x8,
            *(const uint4*)&sH[ch][16 * ct2 + lm][8 * rt + 4 * lg]);
        M[ch] = __builtin_amdgcn_mfma_f32_16x16x32_f16(a2frag, b2, zero4, 0, 0, 0);
    }

    // ---- SSIM pointwise + block reduction ----
    float lsum = 0.f;
    #pragma unroll
    for (int r = 0; r < 4; ++r) {
        const float mx = M[0][r], my = M[1][r];
        const float exx = M[2][r], eyy = M[3][r], exy = M[4][r];
        const float mxx = mx * mx, myy = my * my, mxy = mx * my;
        const float sx  = exx - mxx;
        const float sy  = eyy - myy;
        const float sxy = exy - mxy;
        const float num = (2.0f * mxy + 1e-4f) * (2.0f * sxy + 9e-4f);
        const float den = (mxx + myy + 1e-4f) * (sx + sy + 9e-4f);
        lsum = fmaf(num, __builtin_amdgcn_rcpf(den), lsum);
    }
    #pragma unroll
    for (int off = 32; off > 0; off >>= 1)
        lsum += __shfl_down(lsum, off, 64);
    if (lane == 0) sRed[wv] = lsum;
    __syncthreads();
    if (tid == 0)
        partial[bid] = sRed[0] + sRed[1] + sRed[2] + sRed[3];
}

// ---------------------------------------------------------------------------
// Final reduction: sum partials, out = 1 - mean   (1 block x 1024 threads)
// ---------------------------------------------------------------------------
#define NR 1024
__global__ __launch_bounds__(NR) void ssim_reduce_kernel(
    const float* __restrict__ partial, float* __restrict__ out,
    int n, float inv_npix)
{
    __shared__ float sRed[16];
    float s = 0.0f;
    const int n4 = n >> 2;
    for (int i = threadIdx.x; i < n4; i += NR) {
        const float4 v = ((const float4*)partial)[i];
        s += (v.x + v.y) + (v.z + v.w);
    }
    for (int i = (n4 << 2) + threadIdx.x; i < n; i += NR) s += partial[i];
    #pragma unroll
    for (int off = 32; off > 0; off >>= 1)
        s += __shfl_down(s, off, 64);
    if ((threadIdx.x & 63) == 0) sRed[threadIdx.x >> 6] = s;
    __syncthreads();
    if (threadIdx.x == 0) {
        float tot = 0.0f;
        #pragma unroll
        for (int q = 0; q < 16; ++q) tot += sRed[q];
        out[0] = 1.0f - tot * inv_npix;
    }
}

extern "C" void kernel_launch(void* const* d_in, const int* in_sizes, int n_in,
                              void* d_out, int out_size, void* d_ws, size_t ws_size,
                              hipStream_t stream) {
    const float* pred   = (const float*)d_in[0];
    const float* target = (const float*)d_in[1];
    const float* kern   = (const float*)d_in[2];
    float* out     = (float*)d_out;
    unsigned* tab  = (unsigned*)d_ws;                       // 2 KB band table
    float* partial = (float*)d_ws + WS_PARTIAL_OFF;         // per-block sums

    const int nimg    = in_sizes[0] / (IMG * IMG);          // 64
    const int nblocks = (IMG / BT) * (IMG / BT) * nimg;     // 16384 (mult of 8)
    const float inv_npix = 1.0f / ((float)nimg * (float)(IMG * IMG));

    ssim_init_kernel<<<1, 64, 0, stream>>>(kern, tab);
    ssim_mfma_kernel<<<dim3(nblocks), NT, 0, stream>>>(pred, target, tab, partial);
    ssim_reduce_kernel<<<1, NR, 0, stream>>>(partial, out, nblocks, inv_npix);
}

// Round 11
// 59.593 us; speedup vs baseline: 1.0285x; 1.0285x over previous
//
#include <hip/hip_runtime.h>

#define NT   256
#define IMG  512
#define BT   32     // per-tile output: 32x32; each block does 2 x-adjacent tiles
#define RAWU 24     // raw row stride in uints (48 f16 exactly)
#define HSU  28     // sH col stride in uints (112B)
#define WS_PARTIAL_OFF 1024   // floats; band table occupies first 2KB of ws

typedef _Float16 f16x8 __attribute__((ext_vector_type(8)));
typedef float    f32x4 __attribute__((ext_vector_type(4)));

typedef unsigned (*RawPtr)[48][RAWU];   // [2][48][24] = 9.2 KB (head of union)
typedef unsigned (*HPtr)[BT][HSU];      // [5][32][28] = 17.9 KB (full union)

__device__ inline unsigned pk2(float a, float b) {
    auto r = __builtin_amdgcn_cvt_pkrtz(a, b);     // f32x2 -> f16x2 (RTZ)
    return __builtin_bit_cast(unsigned, r);
}

// ---------------------------------------------------------------------------
// One-time init: per-lane MFMA band fragments for both conv passes -> ws.
// tab[l*8+0..3] = B1 frag (h-conv B operand), tab[l*8+4..7] = A2 frag.
// ---------------------------------------------------------------------------
__global__ void ssim_init_kernel(const float* __restrict__ kern,
                                 unsigned* __restrict__ tab) {
    const int l  = threadIdx.x;        // 0..63
    const int lm = l & 15;
    const int lg = l >> 4;
    const float invg = 1.0f / sqrtf(kern[60]);
    unsigned bu[4], au[4];
    #pragma unroll
    for (int jp = 0; jp < 4; ++jp) {
        const int k0 = 8 * lg + 2 * jp;
        const int d  = k0 - lm - 3;        // B1 band: w[k-n-3]
        const int e  = k0 - lm;            // A2 band: w[k-r]
        float b0 = 0.f, b1 = 0.f, a0 = 0.f, a1 = 0.f;
        if ((unsigned)d       <= 10u) b0 = kern[55 + d] * invg;
        if ((unsigned)(d + 1) <= 10u) b1 = kern[56 + d] * invg;
        if ((unsigned)e       <= 10u) a0 = kern[55 + e] * invg;
        if ((unsigned)(e + 1) <= 10u) a1 = kern[56 + e] * invg;
        bu[jp] = pk2(b0, b1);
        au[jp] = pk2(a0, a1);
    }
    *(uint4*)&tab[l * 8]     = make_uint4(bu[0], bu[1], bu[2], bu[3]);
    *(uint4*)&tab[l * 8 + 4] = make_uint4(au[0], au[1], au[2], au[3]);
}

// ---------------------------------------------------------------------------
// Staging split (T14): LOAD issues 6 float4 global loads into registers;
// WRITE packs to f16 and stores to sRaw. 576 items = 48 rows x (2 img x 6
// col-groups of 8 px); threads 0..63 carry a third item.
// ---------------------------------------------------------------------------
__device__ inline void stage_load(const float* __restrict__ pimg,
                                  const float* __restrict__ timg,
                                  int ty0, int tx, bool inb,
                                  float4 (&pa)[3], float4 (&pb)[3]) {
    const float4 z = make_float4(0.f, 0.f, 0.f, 0.f);
    #pragma unroll
    for (int j = 0; j < 3; ++j) {
        const int i = (int)threadIdx.x + NT * j;
        pa[j] = z; pb[j] = z;
        if (j < 2 || i < 576) {
            const int r  = i / 12;
            const int s  = i - r * 12;
            const int im = s >= 6;
            const int cg = im ? s - 6 : s;
            const float* base = im ? timg : pimg;
            const int gy = ty0 - 5 + r;
            const int gx = tx - 8 + 8 * cg;          // multiple of 4
            if (inb) {
                const float* p = base + gy * IMG + gx;
                pa[j] = *(const float4*)p;
                pb[j] = *(const float4*)(p + 4);
            } else if ((unsigned)gy < IMG) {
                const float* p = base + gy * IMG;
                if ((unsigned)gx < IMG)         pa[j] = *(const float4*)(p + gx);
                if ((unsigned)(gx + 4) < IMG)   pb[j] = *(const float4*)(p + gx + 4);
            }
        }
    }
}

__device__ inline void stage_write(RawPtr sRaw,
                                   const float4 (&pa)[3], const float4 (&pb)[3]) {
    #pragma unroll
    for (int j = 0; j < 3; ++j) {
        const int i = (int)threadIdx.x + NT * j;
        if (j < 2 || i < 576) {
            const int r  = i / 12;
            const int s  = i - r * 12;
            const int im = s >= 6;
            const int cg = im ? s - 6 : s;
            *(uint4*)&sRaw[im][r][4 * cg] =
                make_uint4(pk2(pa[j].x, pa[j].y), pk2(pa[j].z, pa[j].w),
                           pk2(pb[j].x, pb[j].y), pk2(pb[j].z, pb[j].w));
        }
    }
}

// ---------------------------------------------------------------------------
// Per-tile compute (math bit-identical to v4, absmax 0.0039):
//   H-conv:  H[m][16ct+n]   = sum_k raw[m][16ct+k] * B1[k][n],  B1[k][n]=w[k-n-3]
//   V-conv:  out[16rt+r][n] = sum_k A2[r][k] * H[16rt+k][n],    A2[r][k]=w[k-r]
//   PP/TT/PT A-frags derived in-register as products of P/T frags.
// If PRELOAD: issue next tile's staging loads right after sRaw is consumed —
// they drain during H/V-conv (compiler's vmcnt(0) at the next barrier).
// ---------------------------------------------------------------------------
template<bool PRELOAD>
__device__ inline float compute_tile(RawPtr sRaw, HPtr sH,
                                     f16x8 bfrag, f16x8 a2frag,
                                     const float* __restrict__ pimg,
                                     const float* __restrict__ timg,
                                     int ty0, int tx_next, bool inb_next,
                                     float4 (&pa)[3], float4 (&pb)[3]) {
    const int tid  = threadIdx.x;
    const int lane = tid & 63;
    const int wv   = tid >> 6;
    const int lm   = lane & 15;
    const int lg   = lane >> 4;
    const f32x4 zero4 = {0.f, 0.f, 0.f, 0.f};

    // ---- prefetch H-conv A-frags (sH will overwrite sRaw) ----
    const int ct0 = wv & 1, mt0 = wv >> 1;
    const f16x8 aP0 = __builtin_bit_cast(f16x8, *(const uint4*)&sRaw[0][mt0 * 16 + lm][8 * ct0 + 4 * lg]);
    const f16x8 aT0 = __builtin_bit_cast(f16x8, *(const uint4*)&sRaw[1][mt0 * 16 + lm][8 * ct0 + 4 * lg]);
    f16x8 aP1 = aP0, aT1 = aT0;
    if (wv < 2) {
        aP1 = __builtin_bit_cast(f16x8, *(const uint4*)&sRaw[0][32 + lm][8 * wv + 4 * lg]);
        aT1 = __builtin_bit_cast(f16x8, *(const uint4*)&sRaw[1][32 + lm][8 * wv + 4 * lg]);
    }
    __syncthreads();   // sRaw consumed; union region free for sH

    if (PRELOAD)       // T14: issue next tile's loads; hidden under conv below
        stage_load(pimg, timg, ty0, tx_next, inb_next, pa, pb);

    // ---- H-conv: mfma per channel, write h-filtered (f16) column-major ----
    {
        f16x8 af[5];
        af[0] = aP0; af[1] = aT0;
        af[2] = aP0 * aP0;                 // 4x v_pk_mul_f16 each
        af[3] = aT0 * aT0;
        af[4] = aP0 * aT0;
        #pragma unroll
        for (int ch = 0; ch < 5; ++ch) {
            const f32x4 h = __builtin_amdgcn_mfma_f32_16x16x32_f16(af[ch], bfrag, zero4, 0, 0, 0);
            *(uint2*)&sH[ch][16 * ct0 + lm][mt0 * 8 + 2 * lg] =
                make_uint2(pk2(h[0], h[1]), pk2(h[2], h[3]));
        }
    }
    if (wv < 2) {
        f16x8 af[5];
        af[0] = aP1; af[1] = aT1;
        af[2] = aP1 * aP1;
        af[3] = aT1 * aT1;
        af[4] = aP1 * aT1;
        #pragma unroll
        for (int ch = 0; ch < 5; ++ch) {
            const f32x4 h = __builtin_amdgcn_mfma_f32_16x16x32_f16(af[ch], bfrag, zero4, 0, 0, 0);
            *(uint2*)&sH[ch][16 * wv + lm][16 + 2 * lg] =
                make_uint2(pk2(h[0], h[1]), pk2(h[2], h[3]));
        }
    }
    __syncthreads();

    // ---- V-conv: each wave one 16x16 output quadrant, 5 channels ----
    const int rt  = wv >> 1;
    const int ct2 = wv & 1;
    f32x4 M[5];
    #pragma unroll
    for (int ch = 0; ch < 5; ++ch) {
        const f16x8 b2 = __builtin_bit_cast(f16x8,
            *(const uint4*)&sH[ch][16 * ct2 + lm][8 * rt + 4 * lg]);
        M[ch] = __builtin_amdgcn_mfma_f32_16x16x32_f16(a2frag, b2, zero4, 0, 0, 0);
    }

    // ---- SSIM pointwise ----
    float lsum = 0.f;
    #pragma unroll
    for (int r = 0; r < 4; ++r) {
        const float mx = M[0][r], my = M[1][r];
        const float exx = M[2][r], eyy = M[3][r], exy = M[4][r];
        const float mxx = mx * mx, myy = my * my, mxy = mx * my;
        const float sx  = exx - mxx;
        const float sy  = eyy - myy;
        const float sxy = exy - mxy;
        const float num = (2.0f * mxy + 1e-4f) * (2.0f * sxy + 9e-4f);
        const float den = (mxx + myy + 1e-4f) * (sx + sy + 9e-4f);
        lsum = fmaf(num, __builtin_amdgcn_rcpf(den), lsum);
    }
    return lsum;
}

// ---------------------------------------------------------------------------
// SSIM via MFMA, v6 = v4 structure (44.8 us) + 2 tiles/block with T14
// register-held next-tile staging. v5's direct-global frags (61 us) REVERTED:
// per-lane scattered loads on the MFMA critical path regressed 37%.
// ---------------------------------------------------------------------------
__global__ __launch_bounds__(NT, 4) void ssim_mfma_kernel(
    const float* __restrict__ pred,
    const float* __restrict__ target,
    const unsigned* __restrict__ tab,
    float* __restrict__ partial)
{
    __shared__ __align__(16) unsigned sMem[5 * BT * HSU];  // 17.9 KB union
    __shared__ float sRed[4];
    RawPtr sRaw = (RawPtr)sMem;
    HPtr   sH   = (HPtr)sMem;

    const int tid = threadIdx.x;

    // ---- bijective XCD swizzle (gridDim.x % 8 == 0): XCD -> 8 whole images ----
    const int bid   = blockIdx.x;
    const int chunk = (int)gridDim.x >> 3;
    const int swz   = (bid & 7) * chunk + (bid >> 3);
    const int img   = swz >> 7;               // 128 tile-pairs per image
    const int rem   = swz & 127;
    const int ty0   = (rem >> 3) << 5;        // pair row  (16 rows)
    const int txp   = (rem & 7) << 6;         // pair base (8 pairs of 64 px)

    const int lane = tid & 63;

    const float* pimg = pred   + (size_t)img * (IMG * IMG);
    const float* timg = target + (size_t)img * (IMG * IMG);

    // interior: needs rows ty0-5..ty0+42 and cols tx-8..tx+39 in-bounds
    const bool iy   = (unsigned)(ty0 - 5) <= 464u;
    const bool inb0 = iy && ((unsigned)(txp - 8) <= 464u);
    const bool inb1 = iy && ((unsigned)(txp + 24) <= 464u);

    float4 pa[3], pb[3];
    stage_load(pimg, timg, ty0, txp, inb0, pa, pb);      // tile-0 loads first

    const f16x8 bfrag  = __builtin_bit_cast(f16x8, *(const uint4*)&tab[lane * 8]);
    const f16x8 a2frag = __builtin_bit_cast(f16x8, *(const uint4*)&tab[lane * 8 + 4]);

    stage_write(sRaw, pa, pb);
    __syncthreads();

    float lsum = compute_tile<true>(sRaw, sH, bfrag, a2frag, pimg, timg,
                                    ty0, txp + 32, inb1, pa, pb);
    __syncthreads();                 // V-conv(t0) sH reads complete -> union free
    stage_write(sRaw, pa, pb);       // t1 (loads drained during t0 compute)
    __syncthreads();
    lsum += compute_tile<false>(sRaw, sH, bfrag, a2frag, pimg, timg,
                                ty0, 0, false, pa, pb);

    // ---- block reduction -> one partial per block (both tiles) ----
    #pragma unroll
    for (int off = 32; off > 0; off >>= 1)
        lsum += __shfl_down(lsum, off, 64);
    if (lane == 0) sRed[tid >> 6] = lsum;
    __syncthreads();
    if (tid == 0)
        partial[bid] = sRed[0] + sRed[1] + sRed[2] + sRed[3];
}

// ---------------------------------------------------------------------------
// Final reduction: sum partials, out = 1 - mean   (1 block x 1024 threads)
// ---------------------------------------------------------------------------
#define NR 1024
__global__ __launch_bounds__(NR) void ssim_reduce_kernel(
    const float* __restrict__ partial, float* __restrict__ out,
    int n, float inv_npix)
{
    __shared__ float sRed[16];
    float s = 0.0f;
    const int n4 = n >> 2;
    for (int i = threadIdx.x; i < n4; i += NR) {
        const float4 v = ((const float4*)partial)[i];
        s += (v.x + v.y) + (v.z + v.w);
    }
    for (int i = (n4 << 2) + threadIdx.x; i < n; i += NR) s += partial[i];
    #pragma unroll
    for (int off = 32; off > 0; off >>= 1)
        s += __shfl_down(s, off, 64);
    if ((threadIdx.x & 63) == 0) sRed[threadIdx.x >> 6] = s;
    __syncthreads();
    if (threadIdx.x == 0) {
        float tot = 0.0f;
        #pragma unroll
        for (int q = 0; q < 16; ++q) tot += sRed[q];
        out[0] = 1.0f - tot * inv_npix;
    }
}

extern "C" void kernel_launch(void* const* d_in, const int* in_sizes, int n_in,
                              void* d_out, int out_size, void* d_ws, size_t ws_size,
                              hipStream_t stream) {
    const float* pred   = (const float*)d_in[0];
    const float* target = (const float*)d_in[1];
    const float* kern   = (const float*)d_in[2];
    float* out     = (float*)d_out;
    unsigned* tab  = (unsigned*)d_ws;                       // 2 KB band table
    float* partial = (float*)d_ws + WS_PARTIAL_OFF;         // per-block sums

    const int nimg    = in_sizes[0] / (IMG * IMG);          // 64
    const int nblocks = (IMG / BT) * (IMG / 64) * nimg;     // 8192 (mult of 8)
    const float inv_npix = 1.0f / ((float)nimg * (float)(IMG * IMG));

    ssim_init_kernel<<<1, 64, 0, stream>>>(kern, tab);
    ssim_mfma_kernel<<<dim3(nblocks), NT, 0, stream>>>(pred, target, tab, partial);
    ssim_reduce_kernel<<<1, NR, 0, stream>>>(partial, out, nblocks, inv_npix);
}

// Round 12
// 53.602 us; speedup vs baseline: 1.1434x; 1.1118x over previous
//
#include <hip/hip_runtime.h>

#define NT   256
#define IMG  512
#define BT   32     // block output tile: 32x32
#define WS_PARTIAL_OFF 1024   // floats; band table occupies first 2KB of ws

typedef _Float16 f16x8 __attribute__((ext_vector_type(8)));
typedef float    f32x4 __attribute__((ext_vector_type(4)));

__device__ inline unsigned pk2(float a, float b) {
    auto r = __builtin_amdgcn_cvt_pkrtz(a, b);     // f32x2 -> f16x2 (RTZ)
    return __builtin_bit_cast(unsigned, r);
}

// ---------------------------------------------------------------------------
// One-time init: per-lane MFMA band fragments for both conv passes -> ws.
// tab[l*8+0..3] = B1 frag (h-conv B operand), tab[l*8+4..7] = A2 frag.
// ---------------------------------------------------------------------------
__global__ void ssim_init_kernel(const float* __restrict__ kern,
                                 unsigned* __restrict__ tab) {
    const int l  = threadIdx.x;        // 0..63
    const int lm = l & 15;
    const int lg = l >> 4;
    const float invg = 1.0f / sqrtf(kern[60]);
    unsigned bu[4], au[4];
    #pragma unroll
    for (int jp = 0; jp < 4; ++jp) {
        const int k0 = 8 * lg + 2 * jp;
        const int d  = k0 - lm - 3;        // B1 band: w[k-n-3]
        const int e  = k0 - lm;            // A2 band: w[k-r]
        float b0 = 0.f, b1 = 0.f, a0 = 0.f, a1 = 0.f;
        if ((unsigned)d       <= 10u) b0 = kern[55 + d] * invg;
        if ((unsigned)(d + 1) <= 10u) b1 = kern[56 + d] * invg;
        if ((unsigned)e       <= 10u) a0 = kern[55 + e] * invg;
        if ((unsigned)(e + 1) <= 10u) a1 = kern[56 + e] * invg;
        bu[jp] = pk2(b0, b1);
        au[jp] = pk2(a0, a1);
    }
    *(uint4*)&tab[l * 8]     = make_uint4(bu[0], bu[1], bu[2], bu[3]);
    *(uint4*)&tab[l * 8 + 4] = make_uint4(au[0], au[1], au[2], au[3]);
}

// ---------------------------------------------------------------------------
// Staging item: row r = i>>3, col-group cg = i&7 (cg>=6 idle). 8 px of P and
// T, packed f16, written to XOR-swizzled sRaw slots (conflict-free).
// ---------------------------------------------------------------------------
__device__ inline void stage_item(unsigned* sMem,
                                  const float* __restrict__ pimg,
                                  const float* __restrict__ timg,
                                  int ty0, int tx0, bool inb, int i) {
    const int r  = i >> 3;          // 0..47
    const int cg = i & 7;           // 0..7
    if (cg >= 6) return;            // slots 6,7 are swizzle padding
    const int gy = ty0 - 5 + r;
    const int gx = tx0 - 8 + 8 * cg;     // multiple of 4
    float4 p0 = make_float4(0.f, 0.f, 0.f, 0.f), p1 = p0, t0 = p0, t1 = p0;
    if (inb) {
        const float* p = pimg + gy * IMG + gx;
        const float* t = timg + gy * IMG + gx;
        p0 = *(const float4*)p;       p1 = *(const float4*)(p + 4);
        t0 = *(const float4*)t;       t1 = *(const float4*)(t + 4);
    } else if ((unsigned)gy < IMG) {
        const float* p = pimg + gy * IMG;
        const float* t = timg + gy * IMG;
        if ((unsigned)gx < IMG)       { p0 = *(const float4*)(p + gx);
                                        t0 = *(const float4*)(t + gx); }
        if ((unsigned)(gx + 4) < IMG) { p1 = *(const float4*)(p + gx + 4);
                                        t1 = *(const float4*)(t + gx + 4); }
    }
    const int phys = cg ^ (r & 7);                 // T2 XOR swizzle
    const int off  = (r << 5) + (phys << 2);       // uints; rows are 128B
    *(uint4*)&sMem[off] = make_uint4(pk2(p0.x, p0.y), pk2(p0.z, p0.w),
                                     pk2(p1.x, p1.y), pk2(p1.z, p1.w));
    *(uint4*)&sMem[1536 + off] = make_uint4(pk2(t0.x, t0.y), pk2(t0.z, t0.w),
                                            pk2(t1.x, t1.y), pk2(t1.z, t1.w));
}

// ---------------------------------------------------------------------------
// SSIM via MFMA, v7 = v4 (44.8 us) + T2 XOR-swizzled LDS (stride 28 -> 32
// uints, phys_slot = logical ^ (row&7) on both sides). v4's stride-28 "2-way"
// aliasing on b128/b64 ops cost 5.24M conflict cycles (~8.5 us/CU); swizzled
// b128 reads hit all 32 banks per 8-lane group. LDS = 20480 B exactly ->
// still 8 blocks/CU (sRed overlaid in an unused swizzle hole).
// v5 (no LDS staging) and v6 (T14 2-tile) REVERTED: both regressed.
// Math identical to v2..v4 (absmax 0.0039):
//   H-conv:  H[m][16ct+n]   = sum_k raw[m][16ct+k] * B1[k][n],  B1[k][n]=w[k-n-3]
//   V-conv:  out[16rt+r][n] = sum_k A2[r][k] * H[16rt+k][n],    A2[r][k]=w[k-r]
//   PP/TT/PT A-frags derived in-register as products of P/T frags.
// Fragment maps (gfx950 16x16x32): A: lane&15=m, k=(lane>>4)*8+j | B: lane&15=n,
//   same k | C: col=lane&15, row=(lane>>4)*4+reg.
// launch_bounds(256,4): round 4 showed squeezing further spills to scratch.
// ---------------------------------------------------------------------------
__global__ __launch_bounds__(NT, 4) void ssim_mfma_kernel(
    const float* __restrict__ pred,
    const float* __restrict__ target,
    const unsigned* __restrict__ tab,
    float* __restrict__ partial)
{
    // union: sRaw = [2][48 rows][32 uints] (12 KB) ; sH = [5][32 cols][32 uints] (20 KB)
    __shared__ __align__(16) unsigned sMem[5120];   // 20480 B exactly
    float* sRed = (float*)&sMem[24];  // ch0 col0 phys slots 6,7: never touched
                                      // (staging: r=0 -> phys=cg<6; H/V: col&7=0 -> phys=slot<6)

    const int tid = threadIdx.x;

    // ---- bijective XCD swizzle (gridDim.x % 8 == 0): XCD -> 8 whole images ----
    const int bid   = blockIdx.x;
    const int chunk = (int)gridDim.x >> 3;
    const int swz   = (bid & 7) * chunk + (bid >> 3);
    const int img   = swz >> 8;               // 256 tiles per 512x512 image
    const int rem   = swz & 255;
    const int tx0   = (rem & 15) * BT;
    const int ty0   = (rem >> 4) * BT;

    const int lane = tid & 63;
    const int wv   = tid >> 6;
    const int lm   = lane & 15;     // m (A row) / n (B col) / C col
    const int lg   = lane >> 4;     // k-group; C row-group

    // ---- band fragments: two L2-hit vector loads ----
    const f16x8 bfrag  = __builtin_bit_cast(f16x8, *(const uint4*)&tab[lane * 8]);
    const f16x8 a2frag = __builtin_bit_cast(f16x8, *(const uint4*)&tab[lane * 8 + 4]);
    const f32x4 zero4  = {0.f, 0.f, 0.f, 0.f};

    // ---- stage raw P,T (f16) into swizzled LDS: 48 rows x 6 groups of 8 px ----
    {
        const float* pimg = pred   + (size_t)img * (IMG * IMG);
        const float* timg = target + (size_t)img * (IMG * IMG);
        const bool inb = (tx0 > 0) && (tx0 < 480) && (ty0 > 0) && (ty0 < 480);
        stage_item(sMem, pimg, timg, ty0, tx0, inb, tid);
        if (tid < 128) stage_item(sMem, pimg, timg, ty0, tx0, inb, tid + 256);
    }
    __syncthreads();

    // ---- prefetch H-conv A-frags to registers (sH will overwrite sRaw) ----
    // job0 = wv (ct=wv&1, mt=wv>>1); job1 = wv+4 for wv<2 (ct=wv, mt=2)
    const int ct0 = wv & 1, mt0 = wv >> 1;
    const int sl0 = ((2 * ct0 + lg) ^ (lm & 7)) << 2;    // row&7 == lm&7 (mt*16)
    const int ro0 = ((mt0 * 16 + lm) << 5) + sl0;
    const f16x8 aP0 = __builtin_bit_cast(f16x8, *(const uint4*)&sMem[ro0]);
    const f16x8 aT0 = __builtin_bit_cast(f16x8, *(const uint4*)&sMem[1536 + ro0]);
    f16x8 aP1 = aP0, aT1 = aT0;
    if (wv < 2) {
        const int sl1 = ((2 * wv + lg) ^ (lm & 7)) << 2; // ct=wv, mt=2
        const int ro1 = ((32 + lm) << 5) + sl1;
        aP1 = __builtin_bit_cast(f16x8, *(const uint4*)&sMem[ro1]);
        aT1 = __builtin_bit_cast(f16x8, *(const uint4*)&sMem[1536 + ro1]);
    }
    __syncthreads();   // sRaw consumed; union region free for sH

    // ---- H-conv: mfma per channel, write f16 pairs to swizzled sH ----
    // write: col = 16ct+lm; logical uint u0 = 8mt+2lg; phys slot = (u0>>2)^(col&7)
    {
        const int col = 16 * ct0 + lm;
        const int u0  = 8 * mt0 + 2 * lg;
        const int off = (col << 5) + ((((u0 >> 2) ^ (lm & 7)) << 2) | (u0 & 3));
        f16x8 af[5];
        af[0] = aP0; af[1] = aT0;
        af[2] = aP0 * aP0;                 // 4x v_pk_mul_f16 each
        af[3] = aT0 * aT0;
        af[4] = aP0 * aT0;
        #pragma unroll
        for (int ch = 0; ch < 5; ++ch) {
            const f32x4 h = __builtin_amdgcn_mfma_f32_16x16x32_f16(af[ch], bfrag, zero4, 0, 0, 0);
            *(uint2*)&sMem[ch * 1024 + off] = make_uint2(pk2(h[0], h[1]), pk2(h[2], h[3]));
        }
    }
    if (wv < 2) {
        const int col = 16 * wv + lm;          // ct=wv
        const int u0  = 16 + 2 * lg;           // mt=2
        const int off = (col << 5) + ((((u0 >> 2) ^ (lm & 7)) << 2) | (u0 & 3));
        f16x8 af[5];
        af[0] = aP1; af[1] = aT1;
        af[2] = aP1 * aP1;
        af[3] = aT1 * aT1;
        af[4] = aP1 * aT1;
        #pragma unroll
        for (int ch = 0; ch < 5; ++ch) {
            const f32x4 h = __builtin_amdgcn_mfma_f32_16x16x32_f16(af[ch], bfrag, zero4, 0, 0, 0);
            *(uint2*)&sMem[ch * 1024 + off] = make_uint2(pk2(h[0], h[1]), pk2(h[2], h[3]));
        }
    }
    __syncthreads();

    // ---- V-conv: each wave one 16x16 output quadrant, 5 channels ----
    const int rt  = wv >> 1;
    const int ct2 = wv & 1;
    const int colv = 16 * ct2 + lm;
    const int offv = (colv << 5) + (((2 * rt + lg) ^ (lm & 7)) << 2);
    f32x4 M[5];
    #pragma unroll
    for (int ch = 0; ch < 5; ++ch) {
        const f16x8 b2 = __builtin_bit_cast(f16x8, *(const uint4*)&sMem[ch * 1024 + offv]);
        M[ch] = __builtin_amdgcn_mfma_f32_16x16x32_f16(a2frag, b2, zero4, 0, 0, 0);
    }

    // ---- SSIM pointwise + block reduction ----
    float lsum = 0.f;
    #pragma unroll
    for (int r = 0; r < 4; ++r) {
        const float mx = M[0][r], my = M[1][r];
        const float exx = M[2][r], eyy = M[3][r], exy = M[4][r];
        const float mxx = mx * mx, myy = my * my, mxy = mx * my;
        const float sx  = exx - mxx;
        const float sy  = eyy - myy;
        const float sxy = exy - mxy;
        const float num = (2.0f * mxy + 1e-4f) * (2.0f * sxy + 9e-4f);
        const float den = (mxx + myy + 1e-4f) * (sx + sy + 9e-4f);
        lsum = fmaf(num, __builtin_amdgcn_rcpf(den), lsum);
    }
    #pragma unroll
    for (int off = 32; off > 0; off >>= 1)
        lsum += __shfl_down(lsum, off, 64);
    if (lane == 0) sRed[wv] = lsum;
    __syncthreads();
    if (tid == 0)
        partial[bid] = sRed[0] + sRed[1] + sRed[2] + sRed[3];
}

// ---------------------------------------------------------------------------
// Final reduction: sum partials, out = 1 - mean   (1 block x 1024 threads)
// ---------------------------------------------------------------------------
#define NR 1024
__global__ __launch_bounds__(NR) void ssim_reduce_kernel(
    const float* __restrict__ partial, float* __restrict__ out,
    int n, float inv_npix)
{
    __shared__ float sRed[16];
    float s = 0.0f;
    const int n4 = n >> 2;
    for (int i = threadIdx.x; i < n4; i += NR) {
        const float4 v = ((const float4*)partial)[i];
        s += (v.x + v.y) + (v.z + v.w);
    }
    for (int i = (n4 << 2) + threadIdx.x; i < n; i += NR) s += partial[i];
    #pragma unroll
    for (int off = 32; off > 0; off >>= 1)
        s += __shfl_down(s, off, 64);
    if ((threadIdx.x & 63) == 0) sRed[threadIdx.x >> 6] = s;
    __syncthreads();
    if (threadIdx.x == 0) {
        float tot = 0.0f;
        #pragma unroll
        for (int q = 0; q < 16; ++q) tot += sRed[q];
        out[0] = 1.0f - tot * inv_npix;
    }
}

extern "C" void kernel_launch(void* const* d_in, const int* in_sizes, int n_in,
                              void* d_out, int out_size, void* d_ws, size_t ws_size,
                              hipStream_t stream) {
    const float* pred   = (const float*)d_in[0];
    const float* target = (const float*)d_in[1];
    const float* kern   = (const float*)d_in[2];
    float* out     = (float*)d_out;
    unsigned* tab  = (unsigned*)d_ws;                       // 2 KB band table
    float* partial = (float*)d_ws + WS_PARTIAL_OFF;         // per-block sums

    const int nimg    = in_sizes[0] / (IMG * IMG);          // 64
    const int nblocks = (IMG / BT) * (IMG / BT) * nimg;     // 16384 (mult of 8)
    const float inv_npix = 1.0f / ((float)nimg * (float)(IMG * IMG));

    ssim_init_kernel<<<1, 64, 0, stream>>>(kern, tab);
    ssim_mfma_kernel<<<dim3(nblocks), NT, 0, stream>>>(pred, target, tab, partial);
    ssim_reduce_kernel<<<1, NR, 0, stream>>>(partial, out, nblocks, inv_npix);
}

// Round 14
// 45.075 us; speedup vs baseline: 1.3597x; 1.1892x over previous
//
#include <hip/hip_runtime.h>

#define NT   256
#define IMG  512
#define BT   32     // block output tile: 32x32
#define RAWU 28     // raw row stride in uints (112B, 16B-aligned rows)
#define WS_PARTIAL_OFF 1024   // floats; band table occupies first 4KB of ws

typedef _Float16 f16x8 __attribute__((ext_vector_type(8)));
typedef _Float16 f16x4 __attribute__((ext_vector_type(4)));
typedef float    f32x4 __attribute__((ext_vector_type(4)));

__device__ inline unsigned pk2(float a, float b) {
    auto r = __builtin_amdgcn_cvt_pkrtz(a, b);     // f32x2 -> f16x2 (RTZ)
    return __builtin_bit_cast(unsigned, r);
}

// ---------------------------------------------------------------------------
// One-time init: per-lane band fragments -> ws.
//   tab[l*16+0..3]  : B1 frag, K=32 h-conv B operand, B1[k][n]=w[k-n-3]
//   tab[l*16+4..5]  : A2 frag k-tile 0, K=16 v-conv A operand, A2[r][k]=w[k-r]
//   tab[l*16+6..7]  : A2 frag k-tile 1,                        w[k+16-r]
// ---------------------------------------------------------------------------
__global__ void ssim_init_kernel(const float* __restrict__ kern,
                                 unsigned* __restrict__ tab) {
    const int l  = threadIdx.x;        // 0..63
    const int lm = l & 15;
    const int lg = l >> 4;
    const float invg = 1.0f / sqrtf(kern[60]);
    auto wof = [&](int i) -> float {
        return ((unsigned)i <= 10u) ? kern[55 + i] * invg : 0.0f;
    };
    unsigned bu[4];
    #pragma unroll
    for (int jp = 0; jp < 4; ++jp) {
        const int d = 8 * lg + 2 * jp - lm - 3;    // K=32: k=8*lg+2jp+{0,1}
        bu[jp] = pk2(wof(d), wof(d + 1));
    }
    unsigned au[4];
    #pragma unroll
    for (int jp = 0; jp < 2; ++jp) {
        const int e = 4 * lg + 2 * jp - lm;        // K=16: k=4*lg+2jp+{0,1}
        au[jp]     = pk2(wof(e),      wof(e + 1));       // k-tile 0
        au[2 + jp] = pk2(wof(e + 16), wof(e + 17));      // k-tile 1
    }
    *(uint4*)&tab[l * 16]     = make_uint4(bu[0], bu[1], bu[2], bu[3]);
    *(uint4*)&tab[l * 16 + 4] = make_uint4(au[0], au[1], au[2], au[3]);
}

// ---------------------------------------------------------------------------
// SSIM via MFMA, v8: fully in-register H->V chain, NO sH buffer.
// Key identity: the C-output layout of a 16x16x32 MFMA (col=lane&15,
// row=(lane>>4)*4+reg) IS the B-operand layout of a 16x16x16 MFMA
// (col=lane&15, k=(lane>>4)*4+j). So each wave computes its output quadrant's
// H-conv (2 m-tiles x 5 ch, K=32) and feeds the packed C directly into two
// chained K=16 V-conv MFMAs - no LDS handoff, no barriers after staging.
// H rows 16..31 are computed twice (once per rt wave): +10 MFMA/block, cheap.
// v5/v6/v7 (direct-global frags / T14 2-tile / T2 swizzle) all REVERTED:
// each regressed vs v4's 44.8 us.
//   H-conv:  H[m][16ct+n]   = sum_k raw[m][16ct+k] * B1[k][n]
//   V-conv:  out[r][n]      = sum_kt sum_k A2kt[r][k] * H[16rt+16kt+k][n]
//   PP/TT/PT A-frags derived in-register as products of P/T frags.
// launch_bounds(256,4): round 4 showed squeezing further spills to scratch.
// NOTE: K=16 legacy builtin is spelled ...16x16x16f16 (no underscore).
// ---------------------------------------------------------------------------
__global__ __launch_bounds__(NT, 4) void ssim_mfma_kernel(
    const float* __restrict__ pred,
    const float* __restrict__ target,
    const unsigned* __restrict__ tab,
    float* __restrict__ partial)
{
    __shared__ __align__(16) unsigned sRaw[2][48][RAWU];   // 10.75 KB
    __shared__ float sRed[4];

    const int tid = threadIdx.x;

    // ---- bijective XCD swizzle (gridDim.x % 8 == 0): XCD -> 8 whole images ----
    const int bid   = blockIdx.x;
    const int chunk = (int)gridDim.x >> 3;
    const int swz   = (bid & 7) * chunk + (bid >> 3);
    const int img   = swz >> 8;               // 256 tiles per 512x512 image
    const int rem   = swz & 255;
    const int tx0   = (rem & 15) * BT;
    const int ty0   = (rem >> 4) * BT;

    const int lane = tid & 63;
    const int wv   = tid >> 6;
    const int lm   = lane & 15;     // m (A row) / n (B col) / C col
    const int lg   = lane >> 4;     // k-group; C row-group

    // ---- band fragments: two L2-hit vector loads ----
    const uint4 bq = *(const uint4*)&tab[lane * 16];
    const uint4 aq = *(const uint4*)&tab[lane * 16 + 4];
    const f16x8 bfrag = __builtin_bit_cast(f16x8, bq);
    const f16x4 a2k0  = __builtin_bit_cast(f16x4, make_uint2(aq.x, aq.y));
    const f16x4 a2k1  = __builtin_bit_cast(f16x4, make_uint2(aq.z, aq.w));
    const f32x4 zero4 = {0.f, 0.f, 0.f, 0.f};

    // ---- stage raw P,T (f16) into LDS: 48 rows x 6 groups of 8 px (as v4) ----
    {
        const float* pimg = pred   + (size_t)img * (IMG * IMG);
        const float* timg = target + (size_t)img * (IMG * IMG);
        if (tx0 > 0 && tx0 < 480 && ty0 > 0 && ty0 < 480) {
            #pragma unroll
            for (int i = tid; i < 288; i += NT) {
                const int r  = i / 6;
                const int c  = i - r * 6;
                const float* prow = pimg + (ty0 - 5 + r) * IMG + (tx0 - 8 + 8 * c);
                const float* trow = timg + (ty0 - 5 + r) * IMG + (tx0 - 8 + 8 * c);
                const float4 p0 = *(const float4*)(prow);
                const float4 p1 = *(const float4*)(prow + 4);
                const float4 t0 = *(const float4*)(trow);
                const float4 t1 = *(const float4*)(trow + 4);
                const int u = 4 * c;
                *(uint4*)&sRaw[0][r][u] = make_uint4(pk2(p0.x, p0.y), pk2(p0.z, p0.w),
                                                     pk2(p1.x, p1.y), pk2(p1.z, p1.w));
                *(uint4*)&sRaw[1][r][u] = make_uint4(pk2(t0.x, t0.y), pk2(t0.z, t0.w),
                                                     pk2(t1.x, t1.y), pk2(t1.z, t1.w));
            }
        } else {
            for (int i = tid; i < 288; i += NT) {
                const int r  = i / 6;
                const int c  = i - r * 6;
                const int gy = ty0 - 5 + r;
                const int gx = tx0 - 8 + 8 * c;
                float4 p0 = make_float4(0.f, 0.f, 0.f, 0.f), p1 = p0, t0 = p0, t1 = p0;
                if ((unsigned)gy < IMG) {
                    const float* prow = pimg + gy * IMG;
                    const float* trow = timg + gy * IMG;
                    if ((unsigned)gx < IMG) {          // gx % 4 == 0
                        p0 = *(const float4*)(prow + gx);
                        t0 = *(const float4*)(trow + gx);
                    }
                    if ((unsigned)(gx + 4) < IMG) {
                        p1 = *(const float4*)(prow + gx + 4);
                        t1 = *(const float4*)(trow + gx + 4);
                    }
                }
                const int u = 4 * c;
                *(uint4*)&sRaw[0][r][u] = make_uint4(pk2(p0.x, p0.y), pk2(p0.z, p0.w),
                                                     pk2(p1.x, p1.y), pk2(p1.z, p1.w));
                *(uint4*)&sRaw[1][r][u] = make_uint4(pk2(t0.x, t0.y), pk2(t0.z, t0.w),
                                                     pk2(t1.x, t1.y), pk2(t1.z, t1.w));
            }
        }
    }
    __syncthreads();   // the ONLY compute barrier

    // ---- per-wave pipeline: one 16x16 output quadrant (rt, ct2) ----
    const int rt  = wv >> 1;
    const int ct2 = wv & 1;
    const int co  = 8 * ct2;       // k-window col base in uints (raw col 16ct2)

    f16x4 bf0[5], bf1[5];          // V-conv B-frags for k-tiles 0,1

    #pragma unroll
    for (int kt = 0; kt < 2; ++kt) {
        const int rb = 16 * rt + 16 * kt;     // H-conv m-tile base row
        const f16x8 aP = __builtin_bit_cast(f16x8, *(const uint4*)&sRaw[0][rb + lm][co + 4 * lg]);
        const f16x8 aT = __builtin_bit_cast(f16x8, *(const uint4*)&sRaw[1][rb + lm][co + 4 * lg]);
        f16x8 af[5];
        af[0] = aP; af[1] = aT;
        af[2] = aP * aP;                 // 4x v_pk_mul_f16 each
        af[3] = aT * aT;
        af[4] = aP * aT;
        #pragma unroll
        for (int ch = 0; ch < 5; ++ch) {
            const f32x4 h = __builtin_amdgcn_mfma_f32_16x16x32_f16(af[ch], bfrag, zero4, 0, 0, 0);
            const f16x4 b = __builtin_bit_cast(f16x4,
                make_uint2(pk2(h[0], h[1]), pk2(h[2], h[3])));
            if (kt == 0) bf0[ch] = b; else bf1[ch] = b;
        }
    }

    // ---- V-conv: two chained K=16 MFMAs per channel, all in-register ----
    f32x4 M[5];
    #pragma unroll
    for (int ch = 0; ch < 5; ++ch) {
        const f32x4 m0 = __builtin_amdgcn_mfma_f32_16x16x16f16(a2k0, bf0[ch], zero4, 0, 0, 0);
        M[ch]          = __builtin_amdgcn_mfma_f32_16x16x16f16(a2k1, bf1[ch], m0,    0, 0, 0);
    }

    // ---- SSIM pointwise + block reduction ----
    float lsum = 0.f;
    #pragma unroll
    for (int r = 0; r < 4; ++r) {
        const float mx = M[0][r], my = M[1][r];
        const float exx = M[2][r], eyy = M[3][r], exy = M[4][r];
        const float mxx = mx * mx, myy = my * my, mxy = mx * my;
        const float sx  = exx - mxx;
        const float sy  = eyy - myy;
        const float sxy = exy - mxy;
        const float num = (2.0f * mxy + 1e-4f) * (2.0f * sxy + 9e-4f);
        const float den = (mxx + myy + 1e-4f) * (sx + sy + 9e-4f);
        lsum = fmaf(num, __builtin_amdgcn_rcpf(den), lsum);
    }
    #pragma unroll
    for (int off = 32; off > 0; off >>= 1)
        lsum += __shfl_down(lsum, off, 64);
    if (lane == 0) sRed[wv] = lsum;
    __syncthreads();
    if (tid == 0)
        partial[bid] = sRed[0] + sRed[1] + sRed[2] + sRed[3];
}

// ---------------------------------------------------------------------------
// Final reduction: sum partials, out = 1 - mean   (1 block x 1024 threads)
// ---------------------------------------------------------------------------
#define NR 1024
__global__ __launch_bounds__(NR) void ssim_reduce_kernel(
    const float* __restrict__ partial, float* __restrict__ out,
    int n, float inv_npix)
{
    __shared__ float sRed[16];
    float s = 0.0f;
    const int n4 = n >> 2;
    for (int i = threadIdx.x; i < n4; i += NR) {
        const float4 v = ((const float4*)partial)[i];
        s += (v.x + v.y) + (v.z + v.w);
    }
    for (int i = (n4 << 2) + threadIdx.x; i < n; i += NR) s += partial[i];
    #pragma unroll
    for (int off = 32; off > 0; off >>= 1)
        s += __shfl_down(s, off, 64);
    if ((threadIdx.x & 63) == 0) sRed[threadIdx.x >> 6] = s;
    __syncthreads();
    if (threadIdx.x == 0) {
        float tot = 0.0f;
        #pragma unroll
        for (int q = 0; q < 16; ++q) tot += sRed[q];
        out[0] = 1.0f - tot * inv_npix;
    }
}

extern "C" void kernel_launch(void* const* d_in, const int* in_sizes, int n_in,
                              void* d_out, int out_size, void* d_ws, size_t ws_size,
                              hipStream_t stream) {
    const float* pred   = (const float*)d_in[0];
    const float* target = (const float*)d_in[1];
    const float* kern   = (const float*)d_in[2];
    float* out     = (float*)d_out;
    unsigned* tab  = (unsigned*)d_ws;                       // 4 KB band table
    float* partial = (float*)d_ws + WS_PARTIAL_OFF;         // per-block sums

    const int nimg    = in_sizes[0] / (IMG * IMG);          // 64
    const int nblocks = (IMG / BT) * (IMG / BT) * nimg;     // 16384 (mult of 8)
    const float inv_npix = 1.0f / ((float)nimg * (float)(IMG * IMG));

    ssim_init_kernel<<<1, 64, 0, stream>>>(kern, tab);
    ssim_mfma_kernel<<<dim3(nblocks), NT, 0, stream>>>(pred, target, tab, partial);
    ssim_reduce_kernel<<<1, NR, 0, stream>>>(partial, out, nblocks, inv_npix);
}

// Round 15
// 38.248 us; speedup vs baseline: 1.6024x; 1.1785x over previous
//
#include <hip/hip_runtime.h>

#define NT   256
#define IMG  512
#define BT   64     // block output tile: 64x64 (4 waves x 4 rt-quadrants)
#define RAWU 44     // raw row stride in uints (40 data + 4 pad; 8-row bank stagger)
#define WS_PARTIAL_OFF 1024   // floats; band table occupies first 4KB of ws

typedef _Float16 f16x8 __attribute__((ext_vector_type(8)));
typedef _Float16 f16x4 __attribute__((ext_vector_type(4)));
typedef float    f32x4 __attribute__((ext_vector_type(4)));

__device__ inline unsigned pk2(float a, float b) {
    auto r = __builtin_amdgcn_cvt_pkrtz(a, b);     // f32x2 -> f16x2 (RTZ)
    return __builtin_bit_cast(unsigned, r);
}

// ---------------------------------------------------------------------------
// One-time init: per-lane band fragments -> ws (unchanged from v8).
//   tab[l*16+0..3] : B1 frag, K=32 h-conv B operand, B1[k][n]=w[k-n-3]
//   tab[l*16+4..5] : A2 k-tile 0 (K=16 v-conv A), A2[r][k]=w[k-r]
//   tab[l*16+6..7] : A2 k-tile 1,                  w[k+16-r]
// ---------------------------------------------------------------------------
__global__ void ssim_init_kernel(const float* __restrict__ kern,
                                 unsigned* __restrict__ tab) {
    const int l  = threadIdx.x;        // 0..63
    const int lm = l & 15;
    const int lg = l >> 4;
    const float invg = 1.0f / sqrtf(kern[60]);
    auto wof = [&](int i) -> float {
        return ((unsigned)i <= 10u) ? kern[55 + i] * invg : 0.0f;
    };
    unsigned bu[4];
    #pragma unroll
    for (int jp = 0; jp < 4; ++jp) {
        const int d = 8 * lg + 2 * jp - lm - 3;
        bu[jp] = pk2(wof(d), wof(d + 1));
    }
    unsigned au[4];
    #pragma unroll
    for (int jp = 0; jp < 2; ++jp) {
        const int e = 4 * lg + 2 * jp - lm;
        au[jp]     = pk2(wof(e),      wof(e + 1));
        au[2 + jp] = pk2(wof(e + 16), wof(e + 17));
    }
    *(uint4*)&tab[l * 16]     = make_uint4(bu[0], bu[1], bu[2], bu[3]);
    *(uint4*)&tab[l * 16 + 4] = make_uint4(au[0], au[1], au[2], au[3]);
}

// ---------------------------------------------------------------------------
// SSIM via MFMA, v9 = v8's in-register H->V chain scaled to a 64x64 tile.
// v8 (32x32, 45.1 us) was correct but neutral vs v4: with 16384 tiny blocks,
// per-block setup + short dep chains dominate (all pipes <35%). v9 quarters
// the block count: each wave owns a 16-wide col strip x 64 rows; the rolling
// bcur/bnext pipeline computes each of 5 H m-tiles ONCE and feeds quadrant
// rt from m-tiles (rt, rt+1) in-register. Staged rows 74..79 get zero
// V-weight (w[k+16-r] = 0 there), so their content never leaks.
//   H-conv:  H[m][16ct+n] = sum_k raw[m][16ct+k] * B1[k][n]
//   V-conv:  out[16rt+r][n] = sum_j w[j-r] * H[16rt+j][n]  (j in [0,32))
//   PP/TT/PT A-frags derived in-register as products of P/T frags.
// Fragment maps verified rounds 6-14. launch_bounds(256,4): round 4 showed
// tighter caps spill to scratch.
// ---------------------------------------------------------------------------
__global__ __launch_bounds__(NT, 4) void ssim_mfma_kernel(
    const float* __restrict__ pred,
    const float* __restrict__ target,
    const unsigned* __restrict__ tab,
    float* __restrict__ partial)
{
    __shared__ __align__(16) unsigned sRaw[2][80][RAWU];   // 27.5 KB
    __shared__ float sRed[4];

    const int tid = threadIdx.x;

    // ---- bijective XCD swizzle (gridDim.x % 8 == 0) ----
    const int bid   = blockIdx.x;
    const int chunk = (int)gridDim.x >> 3;
    const int swz   = (bid & 7) * chunk + (bid >> 3);
    const int img   = swz >> 6;               // 64 tiles per image
    const int rem   = swz & 63;
    const int tx0   = (rem & 7) * BT;
    const int ty0   = (rem >> 3) * BT;

    const int lane = tid & 63;
    const int wv   = tid >> 6;
    const int lm   = lane & 15;     // m (A row) / n (B col) / C col
    const int lg   = lane >> 4;     // k-group; C row-group

    // ---- band fragments: two L2-hit vector loads ----
    const uint4 bq = *(const uint4*)&tab[lane * 16];
    const uint4 aq = *(const uint4*)&tab[lane * 16 + 4];
    const f16x8 bfrag = __builtin_bit_cast(f16x8, bq);
    const f16x4 a2k0  = __builtin_bit_cast(f16x4, make_uint2(aq.x, aq.y));
    const f16x4 a2k1  = __builtin_bit_cast(f16x4, make_uint2(aq.z, aq.w));
    const f32x4 zero4 = {0.f, 0.f, 0.f, 0.f};

    // ---- stage raw P,T (f16): 80 rows x 10 groups of 8 px ----
    {
        const float* pimg = pred   + (size_t)img * (IMG * IMG);
        const float* timg = target + (size_t)img * (IMG * IMG);
        if ((unsigned)(tx0 - 64) <= 320u && (unsigned)(ty0 - 64) <= 320u) {
            #pragma unroll
            for (int i = tid; i < 800; i += NT) {
                const int r  = i / 10;
                const int cg = i - r * 10;
                const float* prow = pimg + (ty0 - 5 + r) * IMG + (tx0 - 8 + 8 * cg);
                const float* trow = timg + (ty0 - 5 + r) * IMG + (tx0 - 8 + 8 * cg);
                const float4 p0 = *(const float4*)(prow);
                const float4 p1 = *(const float4*)(prow + 4);
                const float4 t0 = *(const float4*)(trow);
                const float4 t1 = *(const float4*)(trow + 4);
                const int u = 4 * cg;
                *(uint4*)&sRaw[0][r][u] = make_uint4(pk2(p0.x, p0.y), pk2(p0.z, p0.w),
                                                     pk2(p1.x, p1.y), pk2(p1.z, p1.w));
                *(uint4*)&sRaw[1][r][u] = make_uint4(pk2(t0.x, t0.y), pk2(t0.z, t0.w),
                                                     pk2(t1.x, t1.y), pk2(t1.z, t1.w));
            }
        } else {
            for (int i = tid; i < 800; i += NT) {
                const int r  = i / 10;
                const int cg = i - r * 10;
                const int gy = ty0 - 5 + r;
                const int gx = tx0 - 8 + 8 * cg;     // multiple of 4
                float4 p0 = make_float4(0.f, 0.f, 0.f, 0.f), p1 = p0, t0 = p0, t1 = p0;
                if ((unsigned)gy < IMG) {
                    const float* prow = pimg + gy * IMG;
                    const float* trow = timg + gy * IMG;
                    if ((unsigned)gx < IMG) {
                        p0 = *(const float4*)(prow + gx);
                        t0 = *(const float4*)(trow + gx);
                    }
                    if ((unsigned)(gx + 4) < IMG) {
                        p1 = *(const float4*)(prow + gx + 4);
                        t1 = *(const float4*)(trow + gx + 4);
                    }
                }
                const int u = 4 * cg;
                *(uint4*)&sRaw[0][r][u] = make_uint4(pk2(p0.x, p0.y), pk2(p0.z, p0.w),
                                                     pk2(p1.x, p1.y), pk2(p1.z, p1.w));
                *(uint4*)&sRaw[1][r][u] = make_uint4(pk2(t0.x, t0.y), pk2(t0.z, t0.w),
                                                     pk2(t1.x, t1.y), pk2(t1.z, t1.w));
            }
        }
    }
    __syncthreads();   // the only compute barrier

    // ---- per-wave: col strip ct = wv; rolling H m-tile pipeline ----
    const int co = 8 * wv;        // k-window uint base (raw px 16*ct)

    #define COMPUTE_H(mt, out)                                                      \
    {                                                                               \
        const f16x8 aP = __builtin_bit_cast(f16x8,                                  \
            *(const uint4*)&sRaw[0][16 * (mt) + lm][co + 4 * lg]);                  \
        const f16x8 aT = __builtin_bit_cast(f16x8,                                  \
            *(const uint4*)&sRaw[1][16 * (mt) + lm][co + 4 * lg]);                  \
        f16x8 af[5];                                                                \
        af[0] = aP; af[1] = aT;                                                     \
        af[2] = aP * aP;                                                            \
        af[3] = aT * aT;                                                            \
        af[4] = aP * aT;                                                            \
        _Pragma("unroll")                                                           \
        for (int ch = 0; ch < 5; ++ch) {                                            \
            const f32x4 h = __builtin_amdgcn_mfma_f32_16x16x32_f16(af[ch], bfrag,   \
                                                                   zero4, 0, 0, 0); \
            out[ch] = __builtin_bit_cast(f16x4,                                     \
                make_uint2(pk2(h[0], h[1]), pk2(h[2], h[3])));                      \
        }                                                                           \
    }

    f16x4 bcur[5], bnext[5];
    COMPUTE_H(0, bcur);

    float lsum = 0.f;
    #pragma unroll
    for (int rt = 0; rt < 4; ++rt) {
        COMPUTE_H(rt + 1, bnext);

        f32x4 M[5];
        #pragma unroll
        for (int ch = 0; ch < 5; ++ch) {
            const f32x4 m0 = __builtin_amdgcn_mfma_f32_16x16x16f16(a2k0, bcur[ch], zero4, 0, 0, 0);
            M[ch]          = __builtin_amdgcn_mfma_f32_16x16x16f16(a2k1, bnext[ch], m0,   0, 0, 0);
        }

        #pragma unroll
        for (int r = 0; r < 4; ++r) {
            const float mx = M[0][r], my = M[1][r];
            const float exx = M[2][r], eyy = M[3][r], exy = M[4][r];
            const float mxx = mx * mx, myy = my * my, mxy = mx * my;
            const float sx  = exx - mxx;
            const float sy  = eyy - myy;
            const float sxy = exy - mxy;
            const float num = (2.0f * mxy + 1e-4f) * (2.0f * sxy + 9e-4f);
            const float den = (mxx + myy + 1e-4f) * (sx + sy + 9e-4f);
            lsum = fmaf(num, __builtin_amdgcn_rcpf(den), lsum);
        }

        #pragma unroll
        for (int ch = 0; ch < 5; ++ch) bcur[ch] = bnext[ch];
    }
    #undef COMPUTE_H

    // ---- block reduction -> one partial per block ----
    #pragma unroll
    for (int off = 32; off > 0; off >>= 1)
        lsum += __shfl_down(lsum, off, 64);
    if (lane == 0) sRed[wv] = lsum;
    __syncthreads();
    if (tid == 0)
        partial[bid] = sRed[0] + sRed[1] + sRed[2] + sRed[3];
}

// ---------------------------------------------------------------------------
// Final reduction: sum partials, out = 1 - mean   (1 block x 1024 threads)
// ---------------------------------------------------------------------------
#define NR 1024
__global__ __launch_bounds__(NR) void ssim_reduce_kernel(
    const float* __restrict__ partial, float* __restrict__ out,
    int n, float inv_npix)
{
    __shared__ float sRed[16];
    float s = 0.0f;
    const int n4 = n >> 2;
    for (int i = threadIdx.x; i < n4; i += NR) {
        const float4 v = ((const float4*)partial)[i];
        s += (v.x + v.y) + (v.z + v.w);
    }
    for (int i = (n4 << 2) + threadIdx.x; i < n; i += NR) s += partial[i];
    #pragma unroll
    for (int off = 32; off > 0; off >>= 1)
        s += __shfl_down(s, off, 64);
    if ((threadIdx.x & 63) == 0) sRed[threadIdx.x >> 6] = s;
    __syncthreads();
    if (threadIdx.x == 0) {
        float tot = 0.0f;
        #pragma unroll
        for (int q = 0; q < 16; ++q) tot += sRed[q];
        out[0] = 1.0f - tot * inv_npix;
    }
}

extern "C" void kernel_launch(void* const* d_in, const int* in_sizes, int n_in,
                              void* d_out, int out_size, void* d_ws, size_t ws_size,
                              hipStream_t stream) {
    const float* pred   = (const float*)d_in[0];
    const float* target = (const float*)d_in[1];
    const float* kern   = (const float*)d_in[2];
    float* out     = (float*)d_out;
    unsigned* tab  = (unsigned*)d_ws;                       // 4 KB band table
    float* partial = (float*)d_ws + WS_PARTIAL_OFF;         // per-block sums

    const int nimg    = in_sizes[0] / (IMG * IMG);          // 64
    const int nblocks = (IMG / BT) * (IMG / BT) * nimg;     // 4096 (mult of 8)
    const float inv_npix = 1.0f / ((float)nimg * (float)(IMG * IMG));

    ssim_init_kernel<<<1, 64, 0, stream>>>(kern, tab);
    ssim_mfma_kernel<<<dim3(nblocks), NT, 0, stream>>>(pred, target, tab, partial);
    ssim_reduce_kernel<<<1, NR, 0, stream>>>(partial, out, nblocks, inv_npix);
}

// Round 16
// 35.792 us; speedup vs baseline: 1.7124x; 1.0686x over previous
//
#include <hip/hip_runtime.h>

#define NT   256
#define IMG  512
#define BT   64     // block output tile: 64x64 (4 waves x 4 rt-quadrants)
#define RAWR 74     // staged rows: 64+10 halo; rows 74..79 have zero V-weight
#define RAWU 44     // raw row stride in uints (40 data + 4; odd*4 -> 2-way banks max)
#define WS_PARTIAL_OFF 1024   // floats; band table occupies first 4KB of ws

typedef _Float16 f16x8 __attribute__((ext_vector_type(8)));
typedef _Float16 f16x4 __attribute__((ext_vector_type(4)));
typedef float    f32x4 __attribute__((ext_vector_type(4)));

__device__ inline unsigned pk2(float a, float b) {
    auto r = __builtin_amdgcn_cvt_pkrtz(a, b);     // f32x2 -> f16x2 (RTZ)
    return __builtin_bit_cast(unsigned, r);
}

// ---------------------------------------------------------------------------
// One-time init: per-lane band fragments -> ws (unchanged from v8/v9).
//   tab[l*16+0..3] : B1 frag, K=32 h-conv B operand, B1[k][n]=w[k-n-3]
//   tab[l*16+4..5] : A2 k-tile 0 (K=16 v-conv A), A2[r][k]=w[k-r]
//   tab[l*16+6..7] : A2 k-tile 1,                  w[k+16-r]
// ---------------------------------------------------------------------------
__global__ void ssim_init_kernel(const float* __restrict__ kern,
                                 unsigned* __restrict__ tab) {
    const int l  = threadIdx.x;        // 0..63
    const int lm = l & 15;
    const int lg = l >> 4;
    const float invg = 1.0f / sqrtf(kern[60]);
    auto wof = [&](int i) -> float {
        return ((unsigned)i <= 10u) ? kern[55 + i] * invg : 0.0f;
    };
    unsigned bu[4];
    #pragma unroll
    for (int jp = 0; jp < 4; ++jp) {
        const int d = 8 * lg + 2 * jp - lm - 3;
        bu[jp] = pk2(wof(d), wof(d + 1));
    }
    unsigned au[4];
    #pragma unroll
    for (int jp = 0; jp < 2; ++jp) {
        const int e = 4 * lg + 2 * jp - lm;
        au[jp]     = pk2(wof(e),      wof(e + 1));
        au[2 + jp] = pk2(wof(e + 16), wof(e + 17));
    }
    *(uint4*)&tab[l * 16]     = make_uint4(bu[0], bu[1], bu[2], bu[3]);
    *(uint4*)&tab[l * 16 + 4] = make_uint4(au[0], au[1], au[2], au[3]);
}

// ---------------------------------------------------------------------------
// SSIM via MFMA, v10 = v9 (38.2 us) with 74 staged rows instead of 80.
// Rows 74..79 only fed mt=4 A-frag reads whose V-weights are exactly 0
// (w[16+q-r], q>=10, r<=15 -> index > 10). Clamping those 6 lanes' reads to
// row 73 (same-address broadcast) leaves the output BIT-IDENTICAL while
// cutting LDS 28.2 -> 25.5 KB => 6 blocks/CU (was 5). Round-15 counters
// showed latency-bound at 40% occupancy -> residency is the binding resource.
//   H-conv:  H[m][16ct+n] = sum_k raw[m][16ct+k] * B1[k][n]
//   V-conv:  out[16rt+r][n] = sum_j w[j-r] * H[16rt+j][n]  (j in [0,32))
//   PP/TT/PT A-frags derived in-register as products of P/T frags.
// Fragment maps verified rounds 6-15. launch_bounds(256,4): round 4 showed
// tighter caps spill to scratch.
// ---------------------------------------------------------------------------
__global__ __launch_bounds__(NT, 4) void ssim_mfma_kernel(
    const float* __restrict__ pred,
    const float* __restrict__ target,
    const unsigned* __restrict__ tab,
    float* __restrict__ partial)
{
    __shared__ __align__(16) unsigned sRaw[2][RAWR][RAWU];   // 25.4 KB
    __shared__ float sRed[4];

    const int tid = threadIdx.x;

    // ---- bijective XCD swizzle (gridDim.x % 8 == 0) ----
    const int bid   = blockIdx.x;
    const int chunk = (int)gridDim.x >> 3;
    const int swz   = (bid & 7) * chunk + (bid >> 3);
    const int img   = swz >> 6;               // 64 tiles per image
    const int rem   = swz & 63;
    const int tx0   = (rem & 7) * BT;
    const int ty0   = (rem >> 3) * BT;

    const int lane = tid & 63;
    const int wv   = tid >> 6;
    const int lm   = lane & 15;     // m (A row) / n (B col) / C col
    const int lg   = lane >> 4;     // k-group; C row-group

    // ---- band fragments: two L2-hit vector loads ----
    const uint4 bq = *(const uint4*)&tab[lane * 16];
    const uint4 aq = *(const uint4*)&tab[lane * 16 + 4];
    const f16x8 bfrag = __builtin_bit_cast(f16x8, bq);
    const f16x4 a2k0  = __builtin_bit_cast(f16x4, make_uint2(aq.x, aq.y));
    const f16x4 a2k1  = __builtin_bit_cast(f16x4, make_uint2(aq.z, aq.w));
    const f32x4 zero4 = {0.f, 0.f, 0.f, 0.f};

    // ---- stage raw P,T (f16): 74 rows x 10 groups of 8 px ----
    {
        const float* pimg = pred   + (size_t)img * (IMG * IMG);
        const float* timg = target + (size_t)img * (IMG * IMG);
        if ((unsigned)(tx0 - 64) <= 320u && (unsigned)(ty0 - 64) <= 320u) {
            #pragma unroll
            for (int i = tid; i < RAWR * 10; i += NT) {
                const int r  = i / 10;
                const int cg = i - r * 10;
                const float* prow = pimg + (ty0 - 5 + r) * IMG + (tx0 - 8 + 8 * cg);
                const float* trow = timg + (ty0 - 5 + r) * IMG + (tx0 - 8 + 8 * cg);
                const float4 p0 = *(const float4*)(prow);
                const float4 p1 = *(const float4*)(prow + 4);
                const float4 t0 = *(const float4*)(trow);
                const float4 t1 = *(const float4*)(trow + 4);
                const int u = 4 * cg;
                *(uint4*)&sRaw[0][r][u] = make_uint4(pk2(p0.x, p0.y), pk2(p0.z, p0.w),
                                                     pk2(p1.x, p1.y), pk2(p1.z, p1.w));
                *(uint4*)&sRaw[1][r][u] = make_uint4(pk2(t0.x, t0.y), pk2(t0.z, t0.w),
                                                     pk2(t1.x, t1.y), pk2(t1.z, t1.w));
            }
        } else {
            for (int i = tid; i < RAWR * 10; i += NT) {
                const int r  = i / 10;
                const int cg = i - r * 10;
                const int gy = ty0 - 5 + r;
                const int gx = tx0 - 8 + 8 * cg;     // multiple of 4
                float4 p0 = make_float4(0.f, 0.f, 0.f, 0.f), p1 = p0, t0 = p0, t1 = p0;
                if ((unsigned)gy < IMG) {
                    const float* prow = pimg + gy * IMG;
                    const float* trow = timg + gy * IMG;
                    if ((unsigned)gx < IMG) {
                        p0 = *(const float4*)(prow + gx);
                        t0 = *(const float4*)(trow + gx);
                    }
                    if ((unsigned)(gx + 4) < IMG) {
                        p1 = *(const float4*)(prow + gx + 4);
                        t1 = *(const float4*)(trow + gx + 4);
                    }
                }
                const int u = 4 * cg;
                *(uint4*)&sRaw[0][r][u] = make_uint4(pk2(p0.x, p0.y), pk2(p0.z, p0.w),
                                                     pk2(p1.x, p1.y), pk2(p1.z, p1.w));
                *(uint4*)&sRaw[1][r][u] = make_uint4(pk2(t0.x, t0.y), pk2(t0.z, t0.w),
                                                     pk2(t1.x, t1.y), pk2(t1.z, t1.w));
            }
        }
    }
    __syncthreads();   // the only compute barrier

    // ---- per-wave: col strip ct = wv; rolling H m-tile pipeline ----
    const int co = 8 * wv;        // k-window uint base (raw px 16*ct)

    // mt=4, lm>=10 reads clamp to row 73: same-address broadcast; those H rows
    // get exactly-zero V-weight, so the result is bit-identical.
    #define COMPUTE_H(mt, out)                                                      \
    {                                                                               \
        const int rr = ((mt) == 4 && lm >= 10) ? 73 : 16 * (mt) + lm;               \
        const f16x8 aP = __builtin_bit_cast(f16x8,                                  \
            *(const uint4*)&sRaw[0][rr][co + 4 * lg]);                              \
        const f16x8 aT = __builtin_bit_cast(f16x8,                                  \
            *(const uint4*)&sRaw[1][rr][co + 4 * lg]);                              \
        f16x8 af[5];                                                                \
        af[0] = aP; af[1] = aT;                                                     \
        af[2] = aP * aP;                                                            \
        af[3] = aT * aT;                                                            \
        af[4] = aP * aT;                                                            \
        _Pragma("unroll")                                                           \
        for (int ch = 0; ch < 5; ++ch) {                                            \
            const f32x4 h = __builtin_amdgcn_mfma_f32_16x16x32_f16(af[ch], bfrag,   \
                                                                   zero4, 0, 0, 0); \
            out[ch] = __builtin_bit_cast(f16x4,                                     \
                make_uint2(pk2(h[0], h[1]), pk2(h[2], h[3])));                      \
        }                                                                           \
    }

    f16x4 bcur[5], bnext[5];
    COMPUTE_H(0, bcur);

    float lsum = 0.f;
    #pragma unroll
    for (int rt = 0; rt < 4; ++rt) {
        COMPUTE_H(rt + 1, bnext);

        f32x4 M[5];
        #pragma unroll
        for (int ch = 0; ch < 5; ++ch) {
            const f32x4 m0 = __builtin_amdgcn_mfma_f32_16x16x16f16(a2k0, bcur[ch], zero4, 0, 0, 0);
            M[ch]          = __builtin_amdgcn_mfma_f32_16x16x16f16(a2k1, bnext[ch], m0,   0, 0, 0);
        }

        #pragma unroll
        for (int r = 0; r < 4; ++r) {
            const float mx = M[0][r], my = M[1][r];
            const float exx = M[2][r], eyy = M[3][r], exy = M[4][r];
            const float mxx = mx * mx, myy = my * my, mxy = mx * my;
            const float sx  = exx - mxx;
            const float sy  = eyy - myy;
            const float sxy = exy - mxy;
            const float num = (2.0f * mxy + 1e-4f) * (2.0f * sxy + 9e-4f);
            const float den = (mxx + myy + 1e-4f) * (sx + sy + 9e-4f);
            lsum = fmaf(num, __builtin_amdgcn_rcpf(den), lsum);
        }

        #pragma unroll
        for (int ch = 0; ch < 5; ++ch) bcur[ch] = bnext[ch];
    }
    #undef COMPUTE_H

    // ---- block reduction -> one partial per block ----
    #pragma unroll
    for (int off = 32; off > 0; off >>= 1)
        lsum += __shfl_down(lsum, off, 64);
    if (lane == 0) sRed[wv] = lsum;
    __syncthreads();
    if (tid == 0)
        partial[bid] = sRed[0] + sRed[1] + sRed[2] + sRed[3];
}

// ---------------------------------------------------------------------------
// Final reduction: sum partials, out = 1 - mean   (1 block x 1024 threads)
// ---------------------------------------------------------------------------
#define NR 1024
__global__ __launch_bounds__(NR) void ssim_reduce_kernel(
    const float* __restrict__ partial, float* __restrict__ out,
    int n, float inv_npix)
{
    __shared__ float sRed[16];
    float s = 0.0f;
    const int n4 = n >> 2;
    for (int i = threadIdx.x; i < n4; i += NR) {
        const float4 v = ((const float4*)partial)[i];
        s += (v.x + v.y) + (v.z + v.w);
    }
    for (int i = (n4 << 2) + threadIdx.x; i < n; i += NR) s += partial[i];
    #pragma unroll
    for (int off = 32; off > 0; off >>= 1)
        s += __shfl_down(s, off, 64);
    if ((threadIdx.x & 63) == 0) sRed[threadIdx.x >> 6] = s;
    __syncthreads();
    if (threadIdx.x == 0) {
        float tot = 0.0f;
        #pragma unroll
        for (int q = 0; q < 16; ++q) tot += sRed[q];
        out[0] = 1.0f - tot * inv_npix;
    }
}

extern "C" void kernel_launch(void* const* d_in, const int* in_sizes, int n_in,
                              void* d_out, int out_size, void* d_ws, size_t ws_size,
                              hipStream_t stream) {
    const float* pred   = (const float*)d_in[0];
    const float* target = (const float*)d_in[1];
    const float* kern   = (const float*)d_in[2];
    float* out     = (float*)d_out;
    unsigned* tab  = (unsigned*)d_ws;                       // 4 KB band table
    float* partial = (float*)d_ws + WS_PARTIAL_OFF;         // per-block sums

    const int nimg    = in_sizes[0] / (IMG * IMG);          // 64
    const int nblocks = (IMG / BT) * (IMG / BT) * nimg;     // 4096 (mult of 8)
    const float inv_npix = 1.0f / ((float)nimg * (float)(IMG * IMG));

    ssim_init_kernel<<<1, 64, 0, stream>>>(kern, tab);
    ssim_mfma_kernel<<<dim3(nblocks), NT, 0, stream>>>(pred, target, tab, partial);
    ssim_reduce_kernel<<<1, NR, 0, stream>>>(partial, out, nblocks, inv_npix);
}